// Round 1
// baseline (220.235 us; speedup 1.0000x reference)
//
#include <hip/hip_runtime.h>

// Problem constants
#define NT 10          // trees
#define NL 16          // leaves per tree
#define NN 31          // nodes per tree
#define DD 256         // hidden dim
#define G4 1024        // 4*D gates
#define NNODES (NT*NN) // 310
#define NPATH (NT*NL)  // 160
#define NB 4096        // batch

// ws layout (floats):
//   xg  [310][1024]  node projections (emb @ W_ih^T + b)
//   hA  [160][256]
//   hB  [160][256]
//   cB  [160][256]

__device__ __forceinline__ float sigf(float x)   { return 1.0f / (1.0f + __expf(-x)); }
__device__ __forceinline__ float tanh_f(float x) { return 2.0f / (1.0f + __expf(-2.0f*x)) - 1.0f; }

// ---------------------------------------------------------------------------
// Kernel A: xg[n][j] = dot(emb[n], W_ih[j]) + b_ih[j] + b_hh[j]
// grid (16 j-tiles of 64, 20 node-tiles of 16), 256 threads.
// Thread: one j, 4 nodes. emb tile staged in LDS (wave-uniform broadcast reads).
// ---------------------------------------------------------------------------
__global__ __launch_bounds__(256) void k_nodeproj(
    const float* __restrict__ emb, const float* __restrict__ Wih,
    const float* __restrict__ bih, const float* __restrict__ bhh,
    float* __restrict__ xg)
{
    __shared__ float4 se[16 * 64];  // 16 nodes x 256 floats
    const int tid   = threadIdx.x;
    const int jt    = blockIdx.x;   // 0..15
    const int ntile = blockIdx.y;   // 0..19

    const float4* emb4 = (const float4*)emb;
    #pragma unroll
    for (int r = 0; r < 4; ++r) {
        int idx = tid + 256 * r;            // 0..1023
        int nl  = idx >> 6;                 // local node 0..15
        int n   = ntile * 16 + nl;
        float4 v = make_float4(0.f, 0.f, 0.f, 0.f);
        if (n < NNODES) v = emb4[n * 64 + (idx & 63)];
        se[idx] = v;
    }
    __syncthreads();

    const int j    = jt * 64 + (tid & 63);
    const int nsub = tid >> 6;              // 0..3
    const float4* W4 = (const float4*)Wih + (size_t)j * 64;
    const float4* e0 = se + (nsub * 4 + 0) * 64;
    const float4* e1 = se + (nsub * 4 + 1) * 64;
    const float4* e2 = se + (nsub * 4 + 2) * 64;
    const float4* e3 = se + (nsub * 4 + 3) * 64;

    float a0 = 0.f, a1 = 0.f, a2 = 0.f, a3 = 0.f;
    #pragma unroll 4
    for (int kc = 0; kc < 64; ++kc) {
        float4 w = W4[kc];
        float4 v0 = e0[kc], v1 = e1[kc], v2 = e2[kc], v3 = e3[kc];
        a0 = fmaf(w.x, v0.x, fmaf(w.y, v0.y, fmaf(w.z, v0.z, fmaf(w.w, v0.w, a0))));
        a1 = fmaf(w.x, v1.x, fmaf(w.y, v1.y, fmaf(w.z, v1.z, fmaf(w.w, v1.w, a1))));
        a2 = fmaf(w.x, v2.x, fmaf(w.y, v2.y, fmaf(w.z, v2.z, fmaf(w.w, v2.w, a2))));
        a3 = fmaf(w.x, v3.x, fmaf(w.y, v3.y, fmaf(w.z, v3.z, fmaf(w.w, v3.w, a3))));
    }
    const float bsum = bih[j] + bhh[j];
    const float acc[4] = {a0, a1, a2, a3};
    #pragma unroll
    for (int i = 0; i < 4; ++i) {
        int n = ntile * 16 + nsub * 4 + i;
        if (n < NNODES) xg[(size_t)n * G4 + j] = acc[i] + bsum;
    }
}

// ---------------------------------------------------------------------------
// LSTM step kernel. SI = 0-based path position of the GEMM input (1..4).
// FIRST: fuse position-0 elementwise step (h0=c0=0) — h1 computed into LDS.
// grid (16 d-tiles of 16, 10 path-groups of 16), 256 threads.
// Thread = (p_local = tid>>4, lane_d = tid&15): computes i,f,g,o for one (p,d).
// 4-way lane duplication on W_hh rows keeps L1 return traffic at 256 B/wave-load.
// h tile in LDS padded to 260-float rows (breaks 4-way bank aliasing).
// ---------------------------------------------------------------------------
template<int SI, bool FIRST>
__global__ __launch_bounds__(256) void k_step(
    const float* __restrict__ xg, const float* __restrict__ Whh,
    const float* __restrict__ h_in, float* __restrict__ h_out,
    float* __restrict__ cbuf)
{
    __shared__ float4 hs4[16 * 65];   // 16 paths x (256+4) floats
    float* hs = (float*)hs4;

    const int tid     = threadIdx.x;
    const int dtile   = blockIdx.x;   // 0..15
    const int pg      = blockIdx.y;   // 0..9
    const int p_local = tid >> 4;     // 0..15
    const int lane_d  = tid & 15;
    const int p = pg * 16 + p_local;
    const int t = p >> 4;             // == pg
    const int l = p & 15;             // == p_local
    const int d = dtile * 16 + lane_d;

    float c_keep = 0.f;
    if (FIRST) {
        // position 0: all paths in this block share the same root node (t*31)
        const float* xr = xg + (size_t)(t * NN) * G4;
        #pragma unroll
        for (int i = 0; i < 16; ++i) {
            int k = lane_d + 16 * i;
            float gi = xr[k], gg = xr[512 + k], go = xr[768 + k];
            float c1 = sigf(gi) * tanh_f(gg);     // c0 = 0 -> forget term drops
            float h1 = sigf(go) * tanh_f(c1);
            hs[p_local * 260 + k] = h1;
            if (i == dtile) c_keep = c1;
        }
    } else {
        const float4* hin4 = (const float4*)h_in;
        #pragma unroll
        for (int r = 0; r < 4; ++r) {
            int idx = tid + 256 * r;              // 0..1023 float4s
            int row = idx >> 6, col = idx & 63;
            hs4[row * 65 + col] = hin4[(size_t)pg * 1024 + idx];
        }
        c_keep = cbuf[(size_t)p * DD + d];
    }
    __syncthreads();

    int off;
    if      (SI == 1) off = 1 + (l >> 3);
    else if (SI == 2) off = 3 + (l >> 2);
    else if (SI == 3) off = 7 + (l >> 1);
    else              off = 15 + l;
    const int node = t * NN + off;

    const float4* W4 = (const float4*)Whh;
    const float4* wi = W4 + (size_t)(d)       * 64;
    const float4* wf = W4 + (size_t)(256 + d) * 64;
    const float4* wg = W4 + (size_t)(512 + d) * 64;
    const float4* wo = W4 + (size_t)(768 + d) * 64;
    const float4* h4 = hs4 + p_local * 65;

    float ai = 0.f, af = 0.f, ag = 0.f, ao = 0.f;
    #pragma unroll 4
    for (int kc = 0; kc < 64; ++kc) {
        float4 h = h4[kc];
        float4 vi = wi[kc], vf = wf[kc], vg = wg[kc], vo = wo[kc];
        ai = fmaf(h.x, vi.x, fmaf(h.y, vi.y, fmaf(h.z, vi.z, fmaf(h.w, vi.w, ai))));
        af = fmaf(h.x, vf.x, fmaf(h.y, vf.y, fmaf(h.z, vf.z, fmaf(h.w, vf.w, af))));
        ag = fmaf(h.x, vg.x, fmaf(h.y, vg.y, fmaf(h.z, vg.z, fmaf(h.w, vg.w, ag))));
        ao = fmaf(h.x, vo.x, fmaf(h.y, vo.y, fmaf(h.z, vo.z, fmaf(h.w, vo.w, ao))));
    }

    const float* xn = xg + (size_t)node * G4;
    float gi = ai + xn[d];
    float gf = af + xn[256 + d];
    float gg = ag + xn[512 + d];
    float go = ao + xn[768 + d];
    float cn = sigf(gf) * c_keep + sigf(gi) * tanh_f(gg);
    float hn = sigf(go) * tanh_f(cn);
    cbuf[(size_t)p * DD + d]  = cn;
    h_out[(size_t)p * DD + d] = hn;
}

// ---------------------------------------------------------------------------
// Scatter: out[b,t,:] = htab[t*16 + argmax(cross[b,t,:]), :]
// One wave per (b,t) row: ballot finds the one-hot leaf, float4 row copy.
// ---------------------------------------------------------------------------
__global__ __launch_bounds__(256) void k_scatter(
    const float* __restrict__ cross, const float* __restrict__ htab,
    float* __restrict__ out)
{
    const int tid  = threadIdx.x;
    const int wave = tid >> 6;
    const int lane = tid & 63;
    const int r = blockIdx.x * 4 + wave;     // 0..40959 = b*10 + t
    const int b = r / NT;
    const int t = r - b * NT;

    float v = 0.f;
    if (lane < NL) v = cross[(size_t)b * (NT * NL) + t * NL + lane];
    unsigned long long m = __ballot(v > 0.5f);
    int leaf = m ? (int)__builtin_ctzll(m) : 0;
    int p = t * NL + leaf;

    const float4* h4 = (const float4*)htab;
    float4* o4 = (float4*)out;
    o4[(size_t)r * 64 + lane] = h4[(size_t)p * 64 + lane];
}

// ---------------------------------------------------------------------------
extern "C" void kernel_launch(void* const* d_in, const int* in_sizes, int n_in,
                              void* d_out, int out_size, void* d_ws, size_t ws_size,
                              hipStream_t stream)
{
    const float* cross = (const float*)d_in[0];
    const float* emb   = (const float*)d_in[1];
    const float* Wih   = (const float*)d_in[2];
    const float* Whh   = (const float*)d_in[3];
    const float* bih   = (const float*)d_in[4];
    const float* bhh   = (const float*)d_in[5];
    float* out = (float*)d_out;

    float* ws = (float*)d_ws;
    float* xg = ws;                          // 310*1024
    float* hA = xg + NNODES * G4;            // 160*256
    float* hB = hA + NPATH * DD;             // 160*256
    float* cB = hB + NPATH * DD;             // 160*256

    hipLaunchKernelGGL(k_nodeproj, dim3(16, 20), dim3(256), 0, stream,
                       emb, Wih, bih, bhh, xg);
    hipLaunchKernelGGL((k_step<1, true>),  dim3(16, 10), dim3(256), 0, stream,
                       xg, Whh, hA, hA, cB);
    hipLaunchKernelGGL((k_step<2, false>), dim3(16, 10), dim3(256), 0, stream,
                       xg, Whh, hA, hB, cB);
    hipLaunchKernelGGL((k_step<3, false>), dim3(16, 10), dim3(256), 0, stream,
                       xg, Whh, hB, hA, cB);
    hipLaunchKernelGGL((k_step<4, false>), dim3(16, 10), dim3(256), 0, stream,
                       xg, Whh, hA, hB, cB);
    hipLaunchKernelGGL(k_scatter, dim3(10240), dim3(256), 0, stream,
                       cross, hB, out);
}